// Round 2
// baseline (112.260 us; speedup 1.0000x reference)
//
#include <hip/hip_runtime.h>

#define HH 32
#define WW 32
#define NB 16
#define NPOS 512
#define TILE 8            // (h,w) positions per block
#define PPAD 516          // padded p-stride in LDS floats: 516 % 32 == 4 -> conflict-free float4 reads
#define NBLK 128          // must all be co-resident (128 blocks x 2 waves on 256 CUs: trivially yes)
#define NLAYERS 4

// Single-use grid barrier: each of the 3 inter-layer barriers has its own
// counter slot, zeroed by a hipMemsetAsync before the kernel (captures fine).
__device__ __forceinline__ void grid_barrier(int* cnt) {
    __syncthreads();                       // all waves of this block done with this layer
    if (threadIdx.x == 0) {
        __threadfence();                   // device-scope release of our state writes
        __hip_atomic_fetch_add(cnt, 1, __ATOMIC_ACQ_REL, __HIP_MEMORY_SCOPE_AGENT);
        while (__hip_atomic_load(cnt, __ATOMIC_ACQUIRE, __HIP_MEMORY_SCOPE_AGENT) < NBLK) {
            __builtin_amdgcn_s_sleep(1);
        }
        __threadfence();                   // acquire: other blocks' writes now visible
    }
    __syncthreads();
}

__global__ __launch_bounds__(128) void asic_fused(
    const float* __restrict__ x,     // (16,32,32)
    const float* __restrict__ tg,    // (4,512,32,32)
    float* __restrict__ bufA,        // ws state ping
    float* __restrict__ bufB,        // ws state pong
    float* __restrict__ out,         // (16,32,32) final
    int* __restrict__ bar)           // 3 zeroed counters
{
    __shared__ float lut[TILE * PPAD];

    const int t   = threadIdx.x;          // 0..127
    const int hw0 = blockIdx.x * TILE;
    const int b   = t >> 3;               // batch 0..15
    const int hwl = t & 7;
    const int h   = hw0 >> 5;
    const int w   = (hw0 & 31) + hwl;

    const float* src = x;

    for (int layer = 0; layer < NLAYERS; ++layer) {
        float* dst = (layer == 3) ? out : ((layer & 1) ? bufB : bufA);
        const float* tgl = tg + (size_t)layer * NPOS * HH * WW;

        // ---- stage sigmoid(tg[layer]) for our 8 positions into LDS
        #pragma unroll
        for (int k = 0; k < 32; ++k) {
            int f   = t + 128 * k;        // 0..4095
            int p   = f >> 3;
            int pos = f & 7;
            float g = tgl[p * (HH * WW) + hw0 + pos];
            lut[pos * PPAD + p] = 1.0f / (1.0f + __expf(-g));
        }

        // ---- gather 3x3 wrapped window from current state (global)
        float c[9];
        const float* sb = src + b * (HH * WW);
        #pragma unroll
        for (int i = 0; i < 3; ++i) {
            int row = ((h + i) & 31) * 32;
            #pragma unroll
            for (int j = 0; j < 3; ++j) {
                c[3 * i + j] = sb[row + ((w + j - 1 + 32) & 31)];
            }
        }

        __syncthreads();   // lut ready

        // ---- v[lo] over m=4..8, u[hi] over m=0..3 (MSB-first)
        float v[32];
        {
            float a2[2], a4[4], a8[8], a16[16];
            a2[0] = 1.0f - c[4]; a2[1] = c[4];
            #pragma unroll
            for (int q = 0; q < 2; ++q)  { a4[2*q]  = a2[q]  * (1.0f - c[5]); a4[2*q+1]  = a2[q]  * c[5]; }
            #pragma unroll
            for (int q = 0; q < 4; ++q)  { a8[2*q]  = a4[q]  * (1.0f - c[6]); a8[2*q+1]  = a4[q]  * c[6]; }
            #pragma unroll
            for (int q = 0; q < 8; ++q)  { a16[2*q] = a8[q]  * (1.0f - c[7]); a16[2*q+1] = a8[q]  * c[7]; }
            #pragma unroll
            for (int q = 0; q < 16; ++q) { v[2*q]   = a16[q] * (1.0f - c[8]); v[2*q+1]   = a16[q] * c[8]; }
        }
        float u[16];
        {
            float a2[2], a4[4], a8[8];
            a2[0] = 1.0f - c[0]; a2[1] = c[0];
            #pragma unroll
            for (int q = 0; q < 2; ++q) { a4[2*q] = a2[q] * (1.0f - c[1]); a4[2*q+1] = a2[q] * c[1]; }
            #pragma unroll
            for (int q = 0; q < 4; ++q) { a8[2*q] = a4[q] * (1.0f - c[2]); a8[2*q+1] = a4[q] * c[2]; }
            #pragma unroll
            for (int q = 0; q < 8; ++q) { u[2*q]  = a8[q] * (1.0f - c[3]); u[2*q+1]  = a8[q] * c[3]; }
        }

        // ---- acc = sum_hi u[hi] * sum_lo v[lo] * lut[hwl][hi*32+lo]
        const float4* lut4 = (const float4*)(lut + hwl * PPAD);
        float acc = 0.0f;
        #pragma unroll
        for (int hi = 0; hi < 16; ++hi) {
            float ps0 = 0.f, ps1 = 0.f, ps2 = 0.f, ps3 = 0.f;
            #pragma unroll
            for (int l4 = 0; l4 < 8; ++l4) {
                float4 L = lut4[hi * 8 + l4];
                ps0 = fmaf(L.x, v[4*l4+0], ps0);
                ps1 = fmaf(L.y, v[4*l4+1], ps1);
                ps2 = fmaf(L.z, v[4*l4+2], ps2);
                ps3 = fmaf(L.w, v[4*l4+3], ps3);
            }
            acc = fmaf(u[hi], (ps0 + ps1) + (ps2 + ps3), acc);
        }

        acc = fminf(fmaxf(acc, 0.0f), 1.0f);
        dst[b * (HH * WW) + h * 32 + w] = acc;

        if (layer < NLAYERS - 1) grid_barrier(bar + layer);
        src = dst;
    }
}

extern "C" void kernel_launch(void* const* d_in, const int* in_sizes, int n_in,
                              void* d_out, int out_size, void* d_ws, size_t ws_size,
                              hipStream_t stream) {
    const float* x  = (const float*)d_in[0];   // (16,32,32)
    const float* tg = (const float*)d_in[1];   // (4,512,32,32)
    float* out  = (float*)d_out;
    float* bufA = (float*)d_ws;                          // 64 KB
    float* bufB = bufA + NB * HH * WW;                   // 64 KB
    int*   bar  = (int*)((char*)d_ws + 256 * 1024);      // 3 counters, well past buffers

    hipMemsetAsync(bar, 0, 4 * sizeof(int), stream);     // zero barrier counters (capture-safe)
    asic_fused<<<NBLK, 128, 0, stream>>>(x, tg, bufA, bufB, out, bar);
}

// Round 3
// 78.296 us; speedup vs baseline: 1.4338x; 1.4338x over previous
//
#include <hip/hip_runtime.h>

#define HH 32
#define WW 32
#define NB 16
#define NPOS 512
#define TILE 8            // (h,w) positions per block (contiguous in w, same row)
#define PPAD 516          // padded p-stride in LDS floats: 516 % 32 == 4 -> conflict-free float4 reads
#define NTHR 512          // 8 waves/block: 4 threads per cell (hi-split)

__global__ __launch_bounds__(NTHR) void asic_layer(
    const float* __restrict__ src,   // (16,32,32) current state
    const float* __restrict__ tg,    // (512,32,32) toggle gates for this layer
    float* __restrict__ dst)         // (16,32,32) next state
{
    __shared__ float lut[TILE * PPAD];   // sigmoid(tg) for our 8 positions
    __shared__ float red[NTHR];          // partial-sum reduction

    const int t   = threadIdx.x;         // 0..511
    const int hw0 = blockIdx.x * TILE;

    // ---- stage sigmoid(tg) for our 8 positions into LDS (8 loads/thread, deep pipeline)
    #pragma unroll
    for (int k = 0; k < 8; ++k) {
        int f   = t + NTHR * k;          // 0..4095
        int p   = f >> 3;
        int pos = f & 7;
        float g = tg[p * (HH * WW) + hw0 + pos];
        lut[pos * PPAD + p] = 1.0f / (1.0f + __expf(-g));
    }

    // ---- each cell (b,hwl) is handled by 4 threads q=0..3 (hi in [4q,4q+4))
    const int c   = t & 127;             // cell 0..127
    const int q   = t >> 7;              // hi-quarter 0..3
    const int b   = c >> 3;              // batch 0..15
    const int hwl = c & 7;
    const int h   = hw0 >> 5;
    const int w   = (hw0 & 31) + hwl;

    // ---- gather 3x3 wrapped window (issued before the sync to overlap latency)
    float cc[9];
    const float* sb = src + b * (HH * WW);
    #pragma unroll
    for (int i = 0; i < 3; ++i) {
        int row = ((h + i) & 31) * 32;
        #pragma unroll
        for (int j = 0; j < 3; ++j) {
            cc[3 * i + j] = sb[row + ((w + j - 1 + 32) & 31)];
        }
    }

    __syncthreads();   // lut ready

    // ---- v[lo] over window elems m=4..8 (MSB-first), u[hi] over m=0..3
    float v[32];
    {
        float a2[2], a4[4], a8[8], a16[16];
        a2[0] = 1.0f - cc[4]; a2[1] = cc[4];
        #pragma unroll
        for (int i = 0; i < 2; ++i)  { a4[2*i]  = a2[i]  * (1.0f - cc[5]); a4[2*i+1]  = a2[i]  * cc[5]; }
        #pragma unroll
        for (int i = 0; i < 4; ++i)  { a8[2*i]  = a4[i]  * (1.0f - cc[6]); a8[2*i+1]  = a4[i]  * cc[6]; }
        #pragma unroll
        for (int i = 0; i < 8; ++i)  { a16[2*i] = a8[i]  * (1.0f - cc[7]); a16[2*i+1] = a8[i]  * cc[7]; }
        #pragma unroll
        for (int i = 0; i < 16; ++i) { v[2*i]   = a16[i] * (1.0f - cc[8]); v[2*i+1]   = a16[i] * cc[8]; }
    }
    float u[16];
    {
        float a2[2], a4[4], a8[8];
        a2[0] = 1.0f - cc[0]; a2[1] = cc[0];
        #pragma unroll
        for (int i = 0; i < 2; ++i) { a4[2*i] = a2[i] * (1.0f - cc[1]); a4[2*i+1] = a2[i] * cc[1]; }
        #pragma unroll
        for (int i = 0; i < 4; ++i) { a8[2*i] = a4[i] * (1.0f - cc[2]); a8[2*i+1] = a4[i] * cc[2]; }
        #pragma unroll
        for (int i = 0; i < 8; ++i) { u[2*i]  = a8[i] * (1.0f - cc[3]); u[2*i+1]  = a8[i] * cc[3]; }
    }

    // ---- partial dot over hi in [4q, 4q+4): 32 broadcast b128 LDS reads + 128 FMA
    const float4* lut4 = (const float4*)(lut + hwl * PPAD);
    float acc = 0.0f;
    #pragma unroll
    for (int hh = 0; hh < 4; ++hh) {
        int hi = 4 * q + hh;
        float ps0 = 0.f, ps1 = 0.f, ps2 = 0.f, ps3 = 0.f;
        #pragma unroll
        for (int l4 = 0; l4 < 8; ++l4) {
            float4 L = lut4[hi * 8 + l4];
            ps0 = fmaf(L.x, v[4*l4+0], ps0);
            ps1 = fmaf(L.y, v[4*l4+1], ps1);
            ps2 = fmaf(L.z, v[4*l4+2], ps2);
            ps3 = fmaf(L.w, v[4*l4+3], ps3);
        }
        acc = fmaf(u[hi], (ps0 + ps1) + (ps2 + ps3), acc);
    }

    red[t] = acc;
    __syncthreads();

    // ---- q=0 threads (t<128) reduce 4 partials, clip, store
    if (t < 128) {
        float s = (red[t] + red[t + 128]) + (red[t + 256] + red[t + 384]);
        s = fminf(fmaxf(s, 0.0f), 1.0f);
        dst[b * (HH * WW) + h * 32 + w] = s;
    }
}

extern "C" void kernel_launch(void* const* d_in, const int* in_sizes, int n_in,
                              void* d_out, int out_size, void* d_ws, size_t ws_size,
                              hipStream_t stream) {
    const float* x  = (const float*)d_in[0];   // (16,32,32)
    const float* tg = (const float*)d_in[1];   // (4,512,32,32)
    float* out = (float*)d_out;                // (16,32,32)
    float* ws  = (float*)d_ws;                 // 64 KB used

    const int grid = (HH * WW) / TILE;         // 128 blocks
    const size_t L = (size_t)NPOS * HH * WW;   // elems per layer of tg

    // ping-pong: x -> ws -> out -> ws -> out  (kernel boundary = coherence point)
    asic_layer<<<grid, NTHR, 0, stream>>>(x,   tg + 0 * L, ws);
    asic_layer<<<grid, NTHR, 0, stream>>>(ws,  tg + 1 * L, out);
    asic_layer<<<grid, NTHR, 0, stream>>>(out, tg + 2 * L, ws);
    asic_layer<<<grid, NTHR, 0, stream>>>(ws,  tg + 3 * L, out);
}